// Round 18
// baseline (119.683 us; speedup 1.0000x reference)
//
#include <hip/hip_runtime.h>
#include <stdint.h>

using bf16   = __bf16;
using bf16x8 = __bf16 __attribute__((ext_vector_type(8)));
using bf16x4 = __bf16 __attribute__((ext_vector_type(4)));
using f32x4  = float  __attribute__((ext_vector_type(4)));
using f32x16 = float  __attribute__((ext_vector_type(16)));
using u32x4  = uint32_t __attribute__((ext_vector_type(4)));

#define DM 1024
#define T_ 2048
#define NH 16

__device__ __forceinline__ void gl_lds16(const void* g, void* l) {
  __builtin_amdgcn_global_load_lds(
      (__attribute__((address_space(1))) void*)g,
      (__attribute__((address_space(3))) void*)l, 16, 0, 0);
}

__device__ __forceinline__ f32x4 mfma16(bf16x8 a, bf16x8 b, f32x4 c) {
  return __builtin_amdgcn_mfma_f32_16x16x32_bf16(a, b, c, 0, 0, 0);
}
__device__ __forceinline__ f32x16 mfma32(bf16x8 a, bf16x8 b, f32x16 c) {
  return __builtin_amdgcn_mfma_f32_32x32x16_bf16(a, b, c, 0, 0, 0);
}
__device__ __forceinline__ uint32_t cvtpk(float lo, float hi) {
  uint32_t r;
  asm volatile("v_cvt_pk_bf16_f32 %0, %1, %2" : "=v"(r) : "v"(lo), "v"(hi));
  return r;
}

// -------- fused prep: x cast (blocks 0..2047) + 4 weight transposes (2048..3071) --------
__global__ __launch_bounds__(256)
void k_prep(const float* __restrict__ x,
            const float* __restrict__ w0, const float* __restrict__ w1,
            const float* __restrict__ w2, const float* __restrict__ w3,
            bf16* __restrict__ xb, bf16* __restrict__ wtq, bf16* __restrict__ wto) {
  __shared__ float tile[64][68];
  const int bid = blockIdx.x;
  if (bid < 2048) {
    const size_t i = (size_t)bid * 256 + threadIdx.x;
    const float4 a = *(const float4*)(x + i * 8);
    const float4 c = *(const float4*)(x + i * 8 + 4);
    bf16x8 v;
    v[0] = (bf16)a.x; v[1] = (bf16)a.y; v[2] = (bf16)a.z; v[3] = (bf16)a.w;
    v[4] = (bf16)c.x; v[5] = (bf16)c.y; v[6] = (bf16)c.z; v[7] = (bf16)c.w;
    *(bf16x8*)(xb + i * 8) = v;
    return;
  }
  const int wblk = bid - 2048;           // 0..1023
  const int z = wblk >> 8;               // weight select
  const int bx = wblk & 15, by = (wblk >> 4) & 15;
  const float* w = (z == 0) ? w0 : (z == 1) ? w1 : (z == 2) ? w2 : w3;
  bf16* wt = (z < 3) ? (wtq + (size_t)z * 1024 * 1024) : wto;
  // fold 1/sqrt(64) * log2(e) into wq so attn softmax runs in exp2 domain
  const float scale = (z == 0) ? 0.125f * 1.44269504f : 1.0f;
  const int tx = threadIdx.x & 15;
  const int ty = threadIdx.x >> 4;
  const int k0 = by * 64, n0 = bx * 64;
#pragma unroll
  for (int j = 0; j < 4; ++j) {
    const int r = ty + 16 * j;
    const float4 v = *(const float4*)(w + (size_t)(k0 + r) * DM + n0 + tx * 4);
    tile[r][tx * 4 + 0] = v.x; tile[r][tx * 4 + 1] = v.y;
    tile[r][tx * 4 + 2] = v.z; tile[r][tx * 4 + 3] = v.w;
  }
  __syncthreads();
#pragma unroll
  for (int j = 0; j < 4; ++j) {
    const int r = ty + 16 * j;
    bf16x4 o;
    o[0] = (bf16)(tile[tx * 4 + 0][r] * scale);
    o[1] = (bf16)(tile[tx * 4 + 1][r] * scale);
    o[2] = (bf16)(tile[tx * 4 + 2][r] * scale);
    o[3] = (bf16)(tile[tx * 4 + 3][r] * scale);
    *(bf16x4*)(wt + (size_t)(n0 + r) * DM + k0 + tx * 4) = o;
  }
}

// ---------------- QKV GEMM: 256x192 tile, 8 waves, counted-vmcnt pipeline ----------------
#define DOMFMA(MG)                                                        \
  do {                                                                    \
    __builtin_amdgcn_s_setprio(1);                                        \
    _Pragma("unroll") for (int ms = 0; ms < 4; ++ms)                      \
      _Pragma("unroll") for (int ns = 0; ns < 3; ++ns)                    \
        acc[(MG) * 4 + ms][ns] =                                          \
            mfma16(af[ms], bfr[ns], acc[(MG) * 4 + ms][ns]);              \
    __builtin_amdgcn_s_setprio(0);                                        \
  } while (0)

__global__ __launch_bounds__(512, 2)
void k_gemm8(const bf16* __restrict__ A, const bf16* __restrict__ BT,
             bf16* __restrict__ Qg, bf16* __restrict__ Kf, bf16* __restrict__ Vf) {
  __shared__ __align__(16) bf16 Ash[2][2][256 * 32];   // [buf][khalf] 16KB each
  __shared__ __align__(16) bf16 Bsh[2][2][192 * 32];   // [buf][khalf] 12KB each
  const int tm = blockIdx.x >> 4, tn = blockIdx.x & 15;
  const int tid = threadIdx.x;
  const int lane = tid & 63, w = tid >> 6;
  const int wr = w >> 2, wc = w & 3;          // 2 x 4 wave grid; per-wave C = 128x48
  const int r16 = lane & 15, g = lane >> 4;
  f32x4 acc[8][3] = {};
  const bf16* Ab = A + (size_t)tm * 256 * DM;
  const bf16* Bb = BT + (size_t)tn * 192 * DM;

  auto stageA = [&](int buf, int kt, int kh) {
#pragma unroll
    for (int j = 0; j < 2; ++j) {
      const int c = tid + 512 * j;            // 16B chunk id, row = c>>2
      gl_lds16(Ab + (size_t)(c >> 2) * DM + kt * 64 + kh * 32 + (c & 3) * 8,
               &Ash[buf][kh][(w * 64 + 512 * j) * 8]);
    }
  };
  auto stageB = [&](int buf, int kt, int kh) {
    {
      const int c = tid;
      gl_lds16(Bb + (size_t)(c >> 2) * DM + kt * 64 + kh * 32 + (c & 3) * 8,
               &Bsh[buf][kh][(w * 64) * 8]);
    }
    if (w < 4) {
      const int c = 512 + tid;
      gl_lds16(Bb + (size_t)(c >> 2) * DM + kt * 64 + kh * 32 + (c & 3) * 8,
               &Bsh[buf][kh][(512 + w * 64) * 8]);
    }
  };
  auto waitp = [&]() {
    if (w < 4) asm volatile("s_waitcnt vmcnt(4)" ::: "memory");
    else       asm volatile("s_waitcnt vmcnt(3)" ::: "memory");
  };
  bf16x8 af[4], bfr[3];
  auto ldA = [&](int buf, int kh, int mgrp) {
#pragma unroll
    for (int ms = 0; ms < 4; ++ms) {
      const int row = wr * 128 + mgrp * 64 + ms * 16 + r16;
      af[ms] = *(const bf16x8*)(&Ash[buf][kh][row * 32 + g * 8]);
    }
  };
  auto ldB = [&](int buf, int kh) {
#pragma unroll
    for (int ns = 0; ns < 3; ++ns) {
      const int row = wc * 48 + ns * 16 + r16;
      bfr[ns] = *(const bf16x8*)(&Bsh[buf][kh][row * 32 + g * 8]);
    }
  };

  stageA(0, 0, 0); stageB(0, 0, 0); stageA(0, 0, 1); stageB(0, 0, 1);
  waitp();
  __builtin_amdgcn_s_barrier();
#pragma unroll 1
  for (int kt = 0; kt < 15; ++kt) {
    const int cur = kt & 1, nxt = cur ^ 1;
    ldB(cur, 0); ldA(cur, 0, 0);
    stageA(nxt, kt + 1, 0);
    DOMFMA(0);
    asm volatile("" ::: "memory");
    __builtin_amdgcn_s_barrier();
    ldA(cur, 0, 1);
    stageB(nxt, kt + 1, 0);
    DOMFMA(1);
    waitp();
    __builtin_amdgcn_s_barrier();
    ldB(cur, 1); ldA(cur, 1, 0);
    stageA(nxt, kt + 1, 1);
    DOMFMA(0);
    asm volatile("" ::: "memory");
    __builtin_amdgcn_s_barrier();
    ldA(cur, 1, 1);
    stageB(nxt, kt + 1, 1);
    DOMFMA(1);
    waitp();
    __builtin_amdgcn_s_barrier();
  }
  asm volatile("s_waitcnt vmcnt(0)" ::: "memory");
  __builtin_amdgcn_s_barrier();
  ldB(1, 0); ldA(1, 0, 0); DOMFMA(0);
  ldA(1, 0, 1);            DOMFMA(1);
  ldB(1, 1); ldA(1, 1, 0); DOMFMA(0);
  ldA(1, 1, 1);            DOMFMA(1);

#pragma unroll
  for (int ms = 0; ms < 8; ++ms) {
#pragma unroll
    for (int ns = 0; ns < 3; ++ns) {
      const int ncol = tn * 192 + wc * 48 + ns * 16 + r16;
      const int m0 = tm * 256 + wr * 128 + ms * 16 + g * 4;   // multiple of 4
      const int which = ncol >> 10, nl = ncol & 1023;
      const int h = nl >> 6, d = nl & 63;
      const int b = m0 >> 11, t0 = m0 & 2047;                 // no b-crossing in r
      const size_t hb = (size_t)(b * NH + h) * (T_ * 64);
      if (which == 2) {
        const int kt = t0 >> 6, s = (t0 & 63) >> 4, hi2 = (t0 >> 3) & 1, j0 = t0 & 7;
        const int dh = d >> 5, d31 = d & 31;
        bf16x4 pv;
#pragma unroll
        for (int r = 0; r < 4; ++r) pv[r] = (bf16)acc[ms][ns][r];
        *(bf16x4*)(Vf + hb + kt * 4096 + (s * 2 + dh) * 512 + (hi2 * 32 + d31) * 8 + j0) = pv;
      } else if (which == 1) {
        const int kt = t0 >> 6, kh2 = (t0 >> 5) & 1;
        const int s = d >> 4, hi2 = (d >> 3) & 1, j = d & 7;
        bf16* base = Kf + hb + kt * 4096 + (s * 2 + kh2) * 512 + hi2 * 256 + j;
#pragma unroll
        for (int r = 0; r < 4; ++r)
          base[((t0 & 31) + r) * 8] = (bf16)acc[ms][ns][r];
      } else {
#pragma unroll
        for (int r = 0; r < 4; ++r)
          Qg[hb + (size_t)(t0 + r) * 64 + d] = (bf16)acc[ms][ns][r];
      }
    }
  }
}

// ---------------- O-proj GEMM (round-12 proven): BK=32, single-buffer, BN=64 ----------------
__global__ __launch_bounds__(256)
void k_gemm1(const bf16* __restrict__ A, const bf16* __restrict__ BT,
             float* __restrict__ Cout) {
  constexpr int BN = 64;
  constexpr int NTW = 2;
  constexpr int TNX = 2;
  __shared__ __align__(16) bf16 Ash[128 * 32];
  __shared__ __align__(16) bf16 Bsh[BN * 32];
  const int xcd = blockIdx.x & 7, idx = blockIdx.x >> 3;
  const int tn = xcd * TNX + idx % TNX;
  const int tm = idx / TNX;
  const int lane = threadIdx.x & 63, w = threadIdx.x >> 6;
  const int wm = w >> 1, wn = w & 1;
  const int r16 = lane & 15, g = lane >> 4;
  f32x4 acc[4][NTW] = {};
  const bf16* Arow = A + (size_t)tm * 128 * DM;
  const bf16* Brow = BT + (size_t)tn * BN * DM;
  for (int k0 = 0; k0 < DM; k0 += 32) {
#pragma unroll
    for (int t = 0; t < 2; ++t) {
      const int q = t * 256 + w * 64 + lane;
      gl_lds16(Arow + (size_t)(q >> 2) * DM + k0 + (q & 3) * 8, Ash + (t * 256 + w * 64) * 8);
    }
    {
      const int q = w * 64 + lane;
      gl_lds16(Brow + (size_t)(q >> 2) * DM + k0 + (q & 3) * 8, Bsh + (w * 64) * 8);
    }
    __syncthreads();
    bf16x8 af[4], bfr[NTW];
#pragma unroll
    for (int mt = 0; mt < 4; ++mt)
      af[mt] = *(const bf16x8*)(Ash + (wm * 64 + mt * 16 + r16) * 32 + g * 8);
#pragma unroll
    for (int nt = 0; nt < NTW; ++nt)
      bfr[nt] = *(const bf16x8*)(Bsh + (wn * (BN / 2) + nt * 16 + r16) * 32 + g * 8);
#pragma unroll
    for (int mt = 0; mt < 4; ++mt)
#pragma unroll
      for (int nt = 0; nt < NTW; ++nt)
        acc[mt][nt] = mfma16(af[mt], bfr[nt], acc[mt][nt]);
    __syncthreads();
  }
#pragma unroll
  for (int mt = 0; mt < 4; ++mt) {
#pragma unroll
    for (int nt = 0; nt < NTW; ++nt) {
      const int ncol = tn * BN + wn * (BN / 2) + nt * 16 + r16;
      const int m0 = tm * 128 + wm * 64 + mt * 16 + g * 4;
#pragma unroll
      for (int r = 0; r < 4; ++r)
        Cout[(size_t)(m0 + r) * DM + ncol] = acc[mt][nt][r];
    }
  }
}

// ---------- flash attention: counted-vmcnt schedule (no vmcnt(0) drain in loop) ----------
// grid 512 (XCD-chunked), 8 waves: qw = w&3 (q-tile of 32 rows), kh = w>>2 (key half).
// Per iter: stage K(i+1) then V(i+1) [K,K,V,V issue order]; QKT(i); exp2(st0);
//   [vmcnt(4)+bar] -> V(i) landed for all waves (outstanding: Vi,Vi, Ki+1 x2, Vi+1 x2);
//   PV(st0); exp2(st1); PV(st1); [vmcnt(2)+bar] -> K(i+1) landed, V(i+1) stays in
//   flight across the barrier. Tail i=15: mid-wait uses vmcnt(0), end-bar skipped.
__global__ __launch_bounds__(512)
void k_attn(const bf16* __restrict__ Qg, const bf16* __restrict__ Kf,
            const bf16* __restrict__ Vf, bf16* __restrict__ Ao) {
  __shared__ __align__(16) bf16 Ksh[2][2][64 * 64];   // [kh][dbuf] 32KB
  __shared__ __align__(16) bf16 Vsh[2][2][64 * 64];   // 32KB
  __shared__ float Lsh[4][64];                        // 1KB
  const int lin = ((blockIdx.x & 7) << 6) | (blockIdx.x >> 3);
  const int bh = lin >> 4, qt = lin & 15;
  const int lane = threadIdx.x & 63, w = threadIdx.x >> 6;
  const int qw = w & 3, kh = w >> 2;
  const int l31 = lane & 31, hi = lane >> 5;
  const bf16* Qb  = Qg + (size_t)bh * T_ * 64;
  const bf16* Kfh = Kf + (size_t)bh * T_ * 64;
  const bf16* Vfh = Vf + (size_t)bh * T_ * 64;
  const int q0 = qt * 128 + qw * 32;
  bf16x8 qb[4];
#pragma unroll
  for (int s = 0; s < 4; ++s)
    qb[s] = *(const bf16x8*)(Qb + (size_t)(q0 + l31) * 64 + s * 16 + hi * 8);
  f32x16 o0 = {}, o1 = {};
  float lacc0 = 0.f, lacc1 = 0.f, lacc2 = 0.f, lacc3 = 0.f;

  // issue order matters for vmcnt counting: K loads first, then V loads
  auto stageK = [&](int buf, int ti) {
#pragma unroll
    for (int j = 0; j < 2; ++j) {
      const int idx = qw * 2 + j;
      gl_lds16(Kfh + (size_t)ti * 4096 + idx * 512 + lane * 8, &Ksh[kh][buf][idx * 512]);
    }
  };
  auto stageV = [&](int buf, int ti) {
#pragma unroll
    for (int j = 0; j < 2; ++j) {
      const int idx = qw * 2 + j;
      gl_lds16(Vfh + (size_t)ti * 4096 + idx * 512 + lane * 8, &Vsh[kh][buf][idx * 512]);
    }
  };
  auto pvstep = [&](const f32x16& sv, int si, const bf16* Vc, int s) {
    uint32_t a0 = cvtpk(sv[si + 0], sv[si + 1]);
    uint32_t a1 = cvtpk(sv[si + 2], sv[si + 3]);
    uint32_t b0 = cvtpk(sv[si + 4], sv[si + 5]);
    uint32_t b1 = cvtpk(sv[si + 6], sv[si + 7]);
    asm volatile("v_permlane32_swap_b32 %0, %1" : "+v"(a0), "+v"(b0));
    asm volatile("v_permlane32_swap_b32 %0, %1" : "+v"(a1), "+v"(b1));
    u32x4 fr; fr[0] = a0; fr[1] = a1; fr[2] = b0; fr[3] = b1;
    const bf16x8 pas = __builtin_bit_cast(bf16x8, fr);
    const bf16x8 v0 = *(const bf16x8*)(Vc + (s * 2 + 0) * 512 + lane * 8);
    const bf16x8 v1 = *(const bf16x8*)(Vc + (s * 2 + 1) * 512 + lane * 8);
    o0 = mfma32(pas, v0, o0);
    o1 = mfma32(pas, v1, o1);
  };

  constexpr int NTH = T_ / 64 / 2;       // 16 tiles per key-half
  // prologue: stage tile0; wait K0 (counted) + barrier; V0 still in flight
  stageK(0, kh * NTH); stageV(0, kh * NTH);
  asm volatile("s_waitcnt vmcnt(2)" ::: "memory");
  __builtin_amdgcn_s_barrier();
#pragma unroll 1
  for (int i = 0; i < NTH; ++i) {
    const int cur = i & 1;
    const bool more = (i + 1 < NTH);
    if (more) { stageK(cur ^ 1, kh * NTH + i + 1); stageV(cur ^ 1, kh * NTH + i + 1); }
    const bf16* Kc = &Ksh[kh][cur][0];
    const bf16* Vc = &Vsh[kh][cur][0];
    f32x16 st0 = {}, st1 = {};
    __builtin_amdgcn_s_setprio(1);
#pragma unroll
    for (int s = 0; s < 4; ++s) {
      const bf16x8 k0 = *(const bf16x8*)(Kc + (s * 2 + 0) * 512 + lane * 8);
      st0 = mfma32(k0, qb[s], st0);
    }
#pragma unroll
    for (int s = 0; s < 4; ++s) {
      const bf16x8 k1 = *(const bf16x8*)(Kc + (s * 2 + 1) * 512 + lane * 8);
      st1 = mfma32(k1, qb[s], st1);
    }
    __builtin_amdgcn_s_setprio(0);
#pragma unroll
    for (int r = 0; r < 16; r += 4) {
      st0[r + 0] = __builtin_amdgcn_exp2f(st0[r + 0]); lacc0 += st0[r + 0];
      st0[r + 1] = __builtin_amdgcn_exp2f(st0[r + 1]); lacc1 += st0[r + 1];
      st0[r + 2] = __builtin_amdgcn_exp2f(st0[r + 2]); lacc2 += st0[r + 2];
      st0[r + 3] = __builtin_amdgcn_exp2f(st0[r + 3]); lacc3 += st0[r + 3];
    }
    // mid-barrier: V(i) landed for ALL waves (own outstanding then: 6 -> keep 4)
    if (more) asm volatile("s_waitcnt vmcnt(4)" ::: "memory");
    else      asm volatile("s_waitcnt vmcnt(0)" ::: "memory");
    __builtin_amdgcn_s_barrier();
    __builtin_amdgcn_s_setprio(1);
    pvstep(st0, 0, Vc, 0);
    pvstep(st0, 8, Vc, 1);
    __builtin_amdgcn_s_setprio(0);
#pragma unroll
    for (int r = 0; r < 16; r += 4) {
      st1[r + 0] = __builtin_amdgcn_exp2f(st1[r + 0]); lacc0 += st1[r + 0];
      st1[r + 1] = __builtin_amdgcn_exp2f(st1[r + 1]); lacc1 += st1[r + 1];
      st1[r + 2] = __builtin_amdgcn_exp2f(st1[r + 2]); lacc2 += st1[r + 2];
      st1[r + 3] = __builtin_amdgcn_exp2f(st1[r + 3]); lacc3 += st1[r + 3];
    }
    __builtin_amdgcn_s_setprio(1);
    pvstep(st1, 0, Vc, 2);
    pvstep(st1, 8, Vc, 3);
    __builtin_amdgcn_s_setprio(0);
    // end-barrier: K(i+1) landed; V(i+1) stays in flight across the barrier
    if (more) {
      asm volatile("s_waitcnt vmcnt(2)" ::: "memory");
      __builtin_amdgcn_s_barrier();
    }
  }
  float llocal = (lacc0 + lacc1) + (lacc2 + lacc3);
  float* cb = (float*)&Ksh[0][0][0] + qw * 2048;   // [32][64] f32 per q-tile
  if (kh == 1) {
#pragma unroll
    for (int r = 0; r < 16; ++r) {
      cb[r * 64 + lane]        = o0[r];
      cb[(16 + r) * 64 + lane] = o1[r];
    }
    Lsh[qw][lane] = llocal;
  }
  __syncthreads();
  if (kh == 0) {
    llocal += Lsh[qw][lane];
#pragma unroll
    for (int r = 0; r < 16; ++r) {
      o0[r] += cb[r * 64 + lane];
      o1[r] += cb[(16 + r) * 64 + lane];
    }
    llocal += __shfl_xor(llocal, 32);
    const int b = bh >> 4, h = bh & 15;
#pragma unroll
    for (int r = 0; r < 16; ++r) {
      const int qoff = (r & 3) + 8 * (r >> 2) + 4 * hi;
      const float linv = 1.f / __shfl(llocal, qoff);
      const size_t base = ((size_t)(b * T_ + q0 + qoff)) * DM + h * 64 + l31;
      Ao[base]      = (bf16)(o0[r] * linv);
      Ao[base + 32] = (bf16)(o1[r] * linv);
    }
  }
}

extern "C" void kernel_launch(void* const* d_in, const int* in_sizes, int n_in,
                              void* d_out, int out_size, void* d_ws, size_t ws_size,
                              hipStream_t stream) {
  const float* x  = (const float*)d_in[0];
  const float* wq = (const float*)d_in[1];
  const float* wk = (const float*)d_in[2];
  const float* wv = (const float*)d_in[3];
  const float* wo = (const float*)d_in[4];
  char* ws = (char*)d_ws;
  const size_t MB = 1024 * 1024;
  bf16* xb   = (bf16*)(ws + 0);        // 8MB: x bf16; reused as attn_out
  bf16* wtq  = (bf16*)(ws + 8 * MB);   // 6MB: [wqT*s; wkT; wvT] = [3072][1024]
  bf16* wto  = (bf16*)(ws + 14 * MB);  // 2MB: woT
  bf16* Qg   = (bf16*)(ws + 16 * MB);  // 8MB [B,H,T,64]
  bf16* Kfb  = (bf16*)(ws + 24 * MB);  // 8MB K fragment-major
  bf16* Vfb  = (bf16*)(ws + 32 * MB);  // 8MB V fragment-major

  k_prep<<<dim3(3072), dim3(256), 0, stream>>>(x, wq, wk, wv, wo, xb, wtq, wto);
  k_gemm8<<<dim3(256), dim3(512), 0, stream>>>(xb, wtq, Qg, Kfb, Vfb);
  k_attn<<<dim3(512), dim3(512), 0, stream>>>(Qg, Kfb, Vfb, xb);
  k_gemm1<<<dim3(512), dim3(256), 0, stream>>>(xb, wto, (float*)d_out);
}

// Round 19
// 118.660 us; speedup vs baseline: 1.0086x; 1.0086x over previous
//
#include <hip/hip_runtime.h>
#include <stdint.h>

using bf16   = __bf16;
using bf16x8 = __bf16 __attribute__((ext_vector_type(8)));
using bf16x4 = __bf16 __attribute__((ext_vector_type(4)));
using f32x4  = float  __attribute__((ext_vector_type(4)));
using f32x16 = float  __attribute__((ext_vector_type(16)));
using u32x4  = uint32_t __attribute__((ext_vector_type(4)));

#define DM 1024
#define T_ 2048
#define NH 16

__device__ __forceinline__ void gl_lds16(const void* g, void* l) {
  __builtin_amdgcn_global_load_lds(
      (__attribute__((address_space(1))) void*)g,
      (__attribute__((address_space(3))) void*)l, 16, 0, 0);
}

__device__ __forceinline__ f32x4 mfma16(bf16x8 a, bf16x8 b, f32x4 c) {
  return __builtin_amdgcn_mfma_f32_16x16x32_bf16(a, b, c, 0, 0, 0);
}
__device__ __forceinline__ f32x16 mfma32(bf16x8 a, bf16x8 b, f32x16 c) {
  return __builtin_amdgcn_mfma_f32_32x32x16_bf16(a, b, c, 0, 0, 0);
}
__device__ __forceinline__ uint32_t cvtpk(float lo, float hi) {
  uint32_t r;
  asm volatile("v_cvt_pk_bf16_f32 %0, %1, %2" : "=v"(r) : "v"(lo), "v"(hi));
  return r;
}

// -------- fused prep: x cast (blocks 0..2047) + 4 weight transposes (2048..3071) --------
__global__ __launch_bounds__(256)
void k_prep(const float* __restrict__ x,
            const float* __restrict__ w0, const float* __restrict__ w1,
            const float* __restrict__ w2, const float* __restrict__ w3,
            bf16* __restrict__ xb, bf16* __restrict__ wtq, bf16* __restrict__ wto) {
  __shared__ float tile[64][68];
  const int bid = blockIdx.x;
  if (bid < 2048) {
    const size_t i = (size_t)bid * 256 + threadIdx.x;
    const float4 a = *(const float4*)(x + i * 8);
    const float4 c = *(const float4*)(x + i * 8 + 4);
    bf16x8 v;
    v[0] = (bf16)a.x; v[1] = (bf16)a.y; v[2] = (bf16)a.z; v[3] = (bf16)a.w;
    v[4] = (bf16)c.x; v[5] = (bf16)c.y; v[6] = (bf16)c.z; v[7] = (bf16)c.w;
    *(bf16x8*)(xb + i * 8) = v;
    return;
  }
  const int wblk = bid - 2048;           // 0..1023
  const int z = wblk >> 8;               // weight select
  const int bx = wblk & 15, by = (wblk >> 4) & 15;
  const float* w = (z == 0) ? w0 : (z == 1) ? w1 : (z == 2) ? w2 : w3;
  bf16* wt = (z < 3) ? (wtq + (size_t)z * 1024 * 1024) : wto;
  // fold 1/sqrt(64) * log2(e) into wq so attn softmax runs in exp2 domain
  const float scale = (z == 0) ? 0.125f * 1.44269504f : 1.0f;
  const int tx = threadIdx.x & 15;
  const int ty = threadIdx.x >> 4;
  const int k0 = by * 64, n0 = bx * 64;
#pragma unroll
  for (int j = 0; j < 4; ++j) {
    const int r = ty + 16 * j;
    const float4 v = *(const float4*)(w + (size_t)(k0 + r) * DM + n0 + tx * 4);
    tile[r][tx * 4 + 0] = v.x; tile[r][tx * 4 + 1] = v.y;
    tile[r][tx * 4 + 2] = v.z; tile[r][tx * 4 + 3] = v.w;
  }
  __syncthreads();
#pragma unroll
  for (int j = 0; j < 4; ++j) {
    const int r = ty + 16 * j;
    bf16x4 o;
    o[0] = (bf16)(tile[tx * 4 + 0][r] * scale);
    o[1] = (bf16)(tile[tx * 4 + 1][r] * scale);
    o[2] = (bf16)(tile[tx * 4 + 2][r] * scale);
    o[3] = (bf16)(tile[tx * 4 + 3][r] * scale);
    *(bf16x4*)(wt + (size_t)(n0 + r) * DM + k0 + tx * 4) = o;
  }
}

// ---------------- QKV GEMM: 256x192 tile, 8 waves, counted-vmcnt pipeline ----------------
// Grid 256 (16x16) = 1 block/CU. BK=64 in two K=32 halves; LDS 113KB.
// Counted waits: never vmcnt(0) inside the loop (waves 0-3: vmcnt(4); 4-7: vmcnt(3)).
#define DOMFMA(MG)                                                        \
  do {                                                                    \
    __builtin_amdgcn_s_setprio(1);                                        \
    _Pragma("unroll") for (int ms = 0; ms < 4; ++ms)                      \
      _Pragma("unroll") for (int ns = 0; ns < 3; ++ns)                    \
        acc[(MG) * 4 + ms][ns] =                                          \
            mfma16(af[ms], bfr[ns], acc[(MG) * 4 + ms][ns]);              \
    __builtin_amdgcn_s_setprio(0);                                        \
  } while (0)

__global__ __launch_bounds__(512, 2)
void k_gemm8(const bf16* __restrict__ A, const bf16* __restrict__ BT,
             bf16* __restrict__ Qg, bf16* __restrict__ Kf, bf16* __restrict__ Vf) {
  __shared__ __align__(16) bf16 Ash[2][2][256 * 32];   // [buf][khalf] 16KB each
  __shared__ __align__(16) bf16 Bsh[2][2][192 * 32];   // [buf][khalf] 12KB each
  const int tm = blockIdx.x >> 4, tn = blockIdx.x & 15;
  const int tid = threadIdx.x;
  const int lane = tid & 63, w = tid >> 6;
  const int wr = w >> 2, wc = w & 3;          // 2 x 4 wave grid; per-wave C = 128x48
  const int r16 = lane & 15, g = lane >> 4;
  f32x4 acc[8][3] = {};
  const bf16* Ab = A + (size_t)tm * 256 * DM;
  const bf16* Bb = BT + (size_t)tn * 192 * DM;

  auto stageA = [&](int buf, int kt, int kh) {
#pragma unroll
    for (int j = 0; j < 2; ++j) {
      const int c = tid + 512 * j;            // 16B chunk id, row = c>>2
      gl_lds16(Ab + (size_t)(c >> 2) * DM + kt * 64 + kh * 32 + (c & 3) * 8,
               &Ash[buf][kh][(w * 64 + 512 * j) * 8]);
    }
  };
  auto stageB = [&](int buf, int kt, int kh) {
    {
      const int c = tid;
      gl_lds16(Bb + (size_t)(c >> 2) * DM + kt * 64 + kh * 32 + (c & 3) * 8,
               &Bsh[buf][kh][(w * 64) * 8]);
    }
    if (w < 4) {
      const int c = 512 + tid;
      gl_lds16(Bb + (size_t)(c >> 2) * DM + kt * 64 + kh * 32 + (c & 3) * 8,
               &Bsh[buf][kh][(512 + w * 64) * 8]);
    }
  };
  auto waitp = [&]() {
    if (w < 4) asm volatile("s_waitcnt vmcnt(4)" ::: "memory");
    else       asm volatile("s_waitcnt vmcnt(3)" ::: "memory");
  };
  bf16x8 af[4], bfr[3];
  auto ldA = [&](int buf, int kh, int mgrp) {
#pragma unroll
    for (int ms = 0; ms < 4; ++ms) {
      const int row = wr * 128 + mgrp * 64 + ms * 16 + r16;
      af[ms] = *(const bf16x8*)(&Ash[buf][kh][row * 32 + g * 8]);
    }
  };
  auto ldB = [&](int buf, int kh) {
#pragma unroll
    for (int ns = 0; ns < 3; ++ns) {
      const int row = wc * 48 + ns * 16 + r16;
      bfr[ns] = *(const bf16x8*)(&Bsh[buf][kh][row * 32 + g * 8]);
    }
  };

  stageA(0, 0, 0); stageB(0, 0, 0); stageA(0, 0, 1); stageB(0, 0, 1);
  waitp();
  __builtin_amdgcn_s_barrier();
#pragma unroll 1
  for (int kt = 0; kt < 15; ++kt) {
    const int cur = kt & 1, nxt = cur ^ 1;
    ldB(cur, 0); ldA(cur, 0, 0);
    stageA(nxt, kt + 1, 0);
    DOMFMA(0);
    asm volatile("" ::: "memory");
    __builtin_amdgcn_s_barrier();
    ldA(cur, 0, 1);
    stageB(nxt, kt + 1, 0);
    DOMFMA(1);
    waitp();
    __builtin_amdgcn_s_barrier();
    ldB(cur, 1); ldA(cur, 1, 0);
    stageA(nxt, kt + 1, 1);
    DOMFMA(0);
    asm volatile("" ::: "memory");
    __builtin_amdgcn_s_barrier();
    ldA(cur, 1, 1);
    stageB(nxt, kt + 1, 1);
    DOMFMA(1);
    waitp();
    __builtin_amdgcn_s_barrier();
  }
  asm volatile("s_waitcnt vmcnt(0)" ::: "memory");
  __builtin_amdgcn_s_barrier();
  ldB(1, 0); ldA(1, 0, 0); DOMFMA(0);
  ldA(1, 0, 1);            DOMFMA(1);
  ldB(1, 1); ldA(1, 1, 0); DOMFMA(0);
  ldA(1, 1, 1);            DOMFMA(1);

#pragma unroll
  for (int ms = 0; ms < 8; ++ms) {
#pragma unroll
    for (int ns = 0; ns < 3; ++ns) {
      const int ncol = tn * 192 + wc * 48 + ns * 16 + r16;
      const int m0 = tm * 256 + wr * 128 + ms * 16 + g * 4;   // multiple of 4
      const int which = ncol >> 10, nl = ncol & 1023;
      const int h = nl >> 6, d = nl & 63;
      const int b = m0 >> 11, t0 = m0 & 2047;                 // no b-crossing in r
      const size_t hb = (size_t)(b * NH + h) * (T_ * 64);
      if (which == 2) {
        const int kt = t0 >> 6, s = (t0 & 63) >> 4, hi2 = (t0 >> 3) & 1, j0 = t0 & 7;
        const int dh = d >> 5, d31 = d & 31;
        bf16x4 pv;
#pragma unroll
        for (int r = 0; r < 4; ++r) pv[r] = (bf16)acc[ms][ns][r];
        *(bf16x4*)(Vf + hb + kt * 4096 + (s * 2 + dh) * 512 + (hi2 * 32 + d31) * 8 + j0) = pv;
      } else if (which == 1) {
        const int kt = t0 >> 6, kh2 = (t0 >> 5) & 1;
        const int s = d >> 4, hi2 = (d >> 3) & 1, j = d & 7;
        bf16* base = Kf + hb + kt * 4096 + (s * 2 + kh2) * 512 + hi2 * 256 + j;
#pragma unroll
        for (int r = 0; r < 4; ++r)
          base[((t0 & 31) + r) * 8] = (bf16)acc[ms][ns][r];
      } else {
#pragma unroll
        for (int r = 0; r < 4; ++r)
          Qg[hb + (size_t)(t0 + r) * 64 + d] = (bf16)acc[ms][ns][r];
      }
    }
  }
}

// ---------------- O-proj GEMM (round-12 proven): BK=32, single-buffer, BN=64 ----------------
__global__ __launch_bounds__(256)
void k_gemm1(const bf16* __restrict__ A, const bf16* __restrict__ BT,
             float* __restrict__ Cout) {
  constexpr int BN = 64;
  constexpr int NTW = 2;
  constexpr int TNX = 2;
  __shared__ __align__(16) bf16 Ash[128 * 32];
  __shared__ __align__(16) bf16 Bsh[BN * 32];
  const int xcd = blockIdx.x & 7, idx = blockIdx.x >> 3;
  const int tn = xcd * TNX + idx % TNX;
  const int tm = idx / TNX;
  const int lane = threadIdx.x & 63, w = threadIdx.x >> 6;
  const int wm = w >> 1, wn = w & 1;
  const int r16 = lane & 15, g = lane >> 4;
  f32x4 acc[4][NTW] = {};
  const bf16* Arow = A + (size_t)tm * 128 * DM;
  const bf16* Brow = BT + (size_t)tn * BN * DM;
  for (int k0 = 0; k0 < DM; k0 += 32) {
#pragma unroll
    for (int t = 0; t < 2; ++t) {
      const int q = t * 256 + w * 64 + lane;
      gl_lds16(Arow + (size_t)(q >> 2) * DM + k0 + (q & 3) * 8, Ash + (t * 256 + w * 64) * 8);
    }
    {
      const int q = w * 64 + lane;
      gl_lds16(Brow + (size_t)(q >> 2) * DM + k0 + (q & 3) * 8, Bsh + (w * 64) * 8);
    }
    __syncthreads();
    bf16x8 af[4], bfr[NTW];
#pragma unroll
    for (int mt = 0; mt < 4; ++mt)
      af[mt] = *(const bf16x8*)(Ash + (wm * 64 + mt * 16 + r16) * 32 + g * 8);
#pragma unroll
    for (int nt = 0; nt < NTW; ++nt)
      bfr[nt] = *(const bf16x8*)(Bsh + (wn * (BN / 2) + nt * 16 + r16) * 32 + g * 8);
#pragma unroll
    for (int mt = 0; mt < 4; ++mt)
#pragma unroll
      for (int nt = 0; nt < NTW; ++nt)
        acc[mt][nt] = mfma16(af[mt], bfr[nt], acc[mt][nt]);
    __syncthreads();
  }
#pragma unroll
  for (int mt = 0; mt < 4; ++mt) {
#pragma unroll
    for (int nt = 0; nt < NTW; ++nt) {
      const int ncol = tn * BN + wn * (BN / 2) + nt * 16 + r16;
      const int m0 = tm * 128 + wm * 64 + mt * 16 + g * 4;
#pragma unroll
      for (int r = 0; r < 4; ++r)
        Cout[(size_t)(m0 + r) * DM + ncol] = acc[mt][nt][r];
    }
  }
}

// ---------- flash attention (round-14 proven): LDS-staged, split-K, in-reg P ----------
__global__ __launch_bounds__(512)
void k_attn(const bf16* __restrict__ Qg, const bf16* __restrict__ Kf,
            const bf16* __restrict__ Vf, bf16* __restrict__ Ao) {
  __shared__ __align__(16) bf16 Ksh[2][2][64 * 64];   // [kh][dbuf] 32KB
  __shared__ __align__(16) bf16 Vsh[2][2][64 * 64];   // 32KB
  __shared__ float Lsh[4][64];                        // 1KB
  const int lin = ((blockIdx.x & 7) << 6) | (blockIdx.x >> 3);
  const int bh = lin >> 4, qt = lin & 15;
  const int lane = threadIdx.x & 63, w = threadIdx.x >> 6;
  const int qw = w & 3, kh = w >> 2;
  const int l31 = lane & 31, hi = lane >> 5;
  const bf16* Qb  = Qg + (size_t)bh * T_ * 64;
  const bf16* Kfh = Kf + (size_t)bh * T_ * 64;
  const bf16* Vfh = Vf + (size_t)bh * T_ * 64;
  const int q0 = qt * 128 + qw * 32;
  bf16x8 qb[4];
#pragma unroll
  for (int s = 0; s < 4; ++s)
    qb[s] = *(const bf16x8*)(Qb + (size_t)(q0 + l31) * 64 + s * 16 + hi * 8);
  f32x16 o0 = {}, o1 = {};
  float lacc0 = 0.f, lacc1 = 0.f, lacc2 = 0.f, lacc3 = 0.f;

  auto stage = [&](int buf, int ti) {
#pragma unroll
    for (int j = 0; j < 2; ++j) {
      const int idx = qw * 2 + j;
      gl_lds16(Kfh + (size_t)ti * 4096 + idx * 512 + lane * 8, &Ksh[kh][buf][idx * 512]);
      gl_lds16(Vfh + (size_t)ti * 4096 + idx * 512 + lane * 8, &Vsh[kh][buf][idx * 512]);
    }
  };
  auto pvstep = [&](const f32x16& sv, int si, const bf16* Vc, int s) {
    uint32_t a0 = cvtpk(sv[si + 0], sv[si + 1]);
    uint32_t a1 = cvtpk(sv[si + 2], sv[si + 3]);
    uint32_t b0 = cvtpk(sv[si + 4], sv[si + 5]);
    uint32_t b1 = cvtpk(sv[si + 6], sv[si + 7]);
    asm volatile("v_permlane32_swap_b32 %0, %1" : "+v"(a0), "+v"(b0));
    asm volatile("v_permlane32_swap_b32 %0, %1" : "+v"(a1), "+v"(b1));
    u32x4 fr; fr[0] = a0; fr[1] = a1; fr[2] = b0; fr[3] = b1;
    const bf16x8 pas = __builtin_bit_cast(bf16x8, fr);
    const bf16x8 v0 = *(const bf16x8*)(Vc + (s * 2 + 0) * 512 + lane * 8);
    const bf16x8 v1 = *(const bf16x8*)(Vc + (s * 2 + 1) * 512 + lane * 8);
    o0 = mfma32(pas, v0, o0);
    o1 = mfma32(pas, v1, o1);
  };

  constexpr int NTH = T_ / 64 / 2;       // 16 tiles per key-half
  stage(0, kh * NTH);
  __syncthreads();
  for (int i = 0; i < NTH; ++i) {
    const int cur = i & 1;
    if (i + 1 < NTH) stage(cur ^ 1, kh * NTH + i + 1);
    const bf16* Kc = &Ksh[kh][cur][0];
    const bf16* Vc = &Vsh[kh][cur][0];
    f32x16 st0 = {}, st1 = {};
    __builtin_amdgcn_s_setprio(1);
#pragma unroll
    for (int s = 0; s < 4; ++s) {
      const bf16x8 k0 = *(const bf16x8*)(Kc + (s * 2 + 0) * 512 + lane * 8);
      st0 = mfma32(k0, qb[s], st0);
    }
#pragma unroll
    for (int s = 0; s < 4; ++s) {
      const bf16x8 k1 = *(const bf16x8*)(Kc + (s * 2 + 1) * 512 + lane * 8);
      st1 = mfma32(k1, qb[s], st1);
    }
    __builtin_amdgcn_s_setprio(0);
#pragma unroll
    for (int r = 0; r < 16; r += 4) {
      st0[r + 0] = __builtin_amdgcn_exp2f(st0[r + 0]); lacc0 += st0[r + 0];
      st0[r + 1] = __builtin_amdgcn_exp2f(st0[r + 1]); lacc1 += st0[r + 1];
      st0[r + 2] = __builtin_amdgcn_exp2f(st0[r + 2]); lacc2 += st0[r + 2];
      st0[r + 3] = __builtin_amdgcn_exp2f(st0[r + 3]); lacc3 += st0[r + 3];
    }
    __builtin_amdgcn_s_setprio(1);
    pvstep(st0, 0, Vc, 0);
    pvstep(st0, 8, Vc, 1);
    __builtin_amdgcn_s_setprio(0);
#pragma unroll
    for (int r = 0; r < 16; r += 4) {
      st1[r + 0] = __builtin_amdgcn_exp2f(st1[r + 0]); lacc0 += st1[r + 0];
      st1[r + 1] = __builtin_amdgcn_exp2f(st1[r + 1]); lacc1 += st1[r + 1];
      st1[r + 2] = __builtin_amdgcn_exp2f(st1[r + 2]); lacc2 += st1[r + 2];
      st1[r + 3] = __builtin_amdgcn_exp2f(st1[r + 3]); lacc3 += st1[r + 3];
    }
    __builtin_amdgcn_s_setprio(1);
    pvstep(st1, 0, Vc, 2);
    pvstep(st1, 8, Vc, 3);
    __builtin_amdgcn_s_setprio(0);
    __syncthreads();
  }
  float llocal = (lacc0 + lacc1) + (lacc2 + lacc3);
  float* cb = (float*)&Ksh[0][0][0] + qw * 2048;   // [32][64] f32 per q-tile
  if (kh == 1) {
#pragma unroll
    for (int r = 0; r < 16; ++r) {
      cb[r * 64 + lane]        = o0[r];
      cb[(16 + r) * 64 + lane] = o1[r];
    }
    Lsh[qw][lane] = llocal;
  }
  __syncthreads();
  if (kh == 0) {
    llocal += Lsh[qw][lane];
#pragma unroll
    for (int r = 0; r < 16; ++r) {
      o0[r] += cb[r * 64 + lane];
      o1[r] += cb[(16 + r) * 64 + lane];
    }
    llocal += __shfl_xor(llocal, 32);
    const int b = bh >> 4, h = bh & 15;
#pragma unroll
    for (int r = 0; r < 16; ++r) {
      const int qoff = (r & 3) + 8 * (r >> 2) + 4 * hi;
      const float linv = 1.f / __shfl(llocal, qoff);
      const size_t base = ((size_t)(b * T_ + q0 + qoff)) * DM + h * 64 + l31;
      Ao[base]      = (bf16)(o0[r] * linv);
      Ao[base + 32] = (bf16)(o1[r] * linv);
    }
  }
}

extern "C" void kernel_launch(void* const* d_in, const int* in_sizes, int n_in,
                              void* d_out, int out_size, void* d_ws, size_t ws_size,
                              hipStream_t stream) {
  const float* x  = (const float*)d_in[0];
  const float* wq = (const float*)d_in[1];
  const float* wk = (const float*)d_in[2];
  const float* wv = (const float*)d_in[3];
  const float* wo = (const float*)d_in[4];
  char* ws = (char*)d_ws;
  const size_t MB = 1024 * 1024;
  bf16* xb   = (bf16*)(ws + 0);        // 8MB: x bf16; reused as attn_out
  bf16* wtq  = (bf16*)(ws + 8 * MB);   // 6MB: [wqT*s; wkT; wvT] = [3072][1024]
  bf16* wto  = (bf16*)(ws + 14 * MB);  // 2MB: woT
  bf16* Qg   = (bf16*)(ws + 16 * MB);  // 8MB [B,H,T,64]
  bf16* Kfb  = (bf16*)(ws + 24 * MB);  // 8MB K fragment-major
  bf16* Vfb  = (bf16*)(ws + 32 * MB);  // 8MB V fragment-major

  k_prep<<<dim3(3072), dim3(256), 0, stream>>>(x, wq, wk, wv, wo, xb, wtq, wto);
  k_gemm8<<<dim3(256), dim3(512), 0, stream>>>(xb, wtq, Qg, Kfb, Vfb);
  k_attn<<<dim3(512), dim3(512), 0, stream>>>(Qg, Kfb, Vfb, xb);
  k_gemm1<<<dim3(512), dim3(256), 0, stream>>>(xb, wto, (float*)d_out);
}